// Round 13
// baseline (1667.164 us; speedup 1.0000x reference)
//
#include <hip/hip_runtime.h>
#include <math.h>

// B=4, H=256, W=256, 100 iters. Closed-form update (3-pt GH quadrature is
// exact for these degree<=4 integrands; log/NDC terms cancel):
//   dmu  = 2*uw1*mu + uw2*y + sum_edges ew*mu_nb
//   dsg  = 2*uw1*sg + sum_edges ew*rou_edge*sg_nb
//   drou = ew*sg_self*sg_nb        (per owned edge)
// Temporal blocking, T=10 iters/launch, 10 launches (kernel boundary = the
// cheapest cross-XCD coherence mechanism on gfx950 — r10/r11/r12 showed all
// in-kernel barrier+exchange schemes cost 160-1700 us extra via L2 flushes
// or uncached atomics).
// Round 13: hide the global load phase via block oversubscription.
// 512 blocks x 512 threads, interior 32(cols)x16(rows), tile 52x36,
// SINGLE-buffered LDS (30.5 KB) -> 2+ co-resident blocks/CU: one block's
// tile load overlaps another's LDS iteration loop (r8 had 88 KB LDS -> 1
// block/CU -> ~10 us serial load per launch). Trade: halo ratio 3.66x vs
// 2.64x (+38% inner work) + 2 syncs/iter; win: load phase off the critical
// path. __launch_bounds__(512,8) pins VGPR<=64 (r8's state fit in 64).
#define NPIX  262144
#define NEDGE 524288
#define ITERS 100
#define T     10
#define TW    52            // tile cols  (32 + 2*T)
#define TH    36            // tile rows  (16 + 2*T)
#define TS    53            // padded LDS row stride (float4 units)
#define NRG   9             // rowgroups of 4 rows: 9*4 = 36 exact
#define ACTIVE (TW*NRG)     // 468 active threads of 512
#define CLO   T             // interior cols [10, 42)
#define CHI   (T+32)
#define RLO   T             // interior rows [10, 26)
#define RHI   (T+16)

__device__ __forceinline__ float clampf(float x, float lo, float hi) {
    return fminf(fmaxf(x, lo), hi);
}

// State float4 {mu, sigma, rou0(down-edge), rou1(right-edge)}.
// c1 = {2*uw1, uw2*y, ew0, ew1}.
__global__ __launch_bounds__(512, 8) void tile_kernel(
    const float4* __restrict__ stI, const float4* __restrict__ vI,
    float4* __restrict__ stO, float4* __restrict__ vO,
    const float4* __restrict__ c1,
    float* __restrict__ mu_out,   // non-null on last launch (st/v not stored)
    int first)                    // launch 0: v := 0, vI not read
{
    __shared__ float4 buf[TH*TS];   // 30.5 KB single-buffered

    int tid = threadIdx.x;
    int rg  = tid / TW;
    int col = tid - rg*TW;
    bool act = (tid < ACTIVE);
    int bz = blockIdx.z;
    int h0 = blockIdx.y * 16;
    int w0 = blockIdx.x * 32;
    int w  = (w0 + col - T) & 255;
    bool cin = (col >= CLO) && (col < CHI);

    float4 st[4], v[4], k1[4];
    float2 k2[4];
    int gidx[4];

    // ---- load: st/v/c1 -> regs; stage {ew0,ew1} through buf for k2 ----
    float2* ews = (float2*)&buf[0];   // float2 view, overwritten later
    if (act) {
#pragma unroll
        for (int k = 0; k < 4; ++k) {
            int r = 4*rg + k;
            int h = (h0 + r - T) & 255;
            int g = (bz << 16) | (h << 8) | w;
            gidx[k] = g;
            st[k] = stI[g];
            float4 K = c1[g];
            k1[k] = K;
            ews[r*TS + col] = make_float2(K.z, K.w);   // {ew0, ew1}
            v[k] = first ? make_float4(0.f, 0.f, 0.f, 0.f) : vI[g];
        }
    }
    __syncthreads();

    int cl = (col == 0)     ? 0     : col-1;
    int cr = (col == TW-1)  ? TW-1  : col+1;
    if (act) {
#pragma unroll
        for (int k = 0; k < 4; ++k) {
            int r  = 4*rg + k;
            int ru = (r == 0) ? 0 : r-1;
            k2[k] = make_float2(ews[ru*TS + col].x, ews[r*TS + cl].y);
        }
    }
    __syncthreads();   // k2 staging reads done

    // populate tile with st
    if (act) {
#pragma unroll
        for (int k = 0; k < 4; ++k)
            buf[(4*rg + k)*TS + col] = st[k];
    }
    __syncthreads();

    // ---- T fused Jacobi iterations, single buffer, 2 barriers each ----
    for (int s = 0; s < T; ++s) {
        float4 ns[4];
        if (act) {
            int r0 = 4*rg;
            float4 up0 = buf[((rg == 0) ? 0 : (r0-1))*TS + col];
            float4 dn3 = buf[((rg == NRG-1) ? (TH-1) : (r0+4))*TS + col];
#pragma unroll
            for (int k = 0; k < 4; ++k) {
                int r = r0 + k;
                float4 lf = buf[r*TS + cl];
                float4 rt = buf[r*TS + cr];
                float4 up = (k == 0) ? up0 : st[k-1];
                float4 dn = (k == 3) ? dn3 : st[k+1];
                float4 S  = st[k];
                float4 K  = k1[k];
                float2 K2 = k2[k];
                float dmu = K.x*S.x + K.y + K.z*dn.x + K.w*rt.x
                          + K2.x*up.x + K2.y*lf.x;
                float dsg = K.x*S.y + K.z*S.z*dn.y + K.w*S.w*rt.y
                          + K2.x*up.z*up.y + K2.y*lf.w*lf.y;
                float dr0 = K.z*S.y*dn.y;
                float dr1 = K.w*S.y*rt.y;
                float4 V = v[k];
                V.x = 0.7f*V.x + 0.01f*dmu;
                V.y = 0.7f*V.y + 0.01f*dsg;
                V.z = 0.7f*V.z + 0.01f*dr0;
                V.w = 0.7f*V.w + 0.01f*dr1;
                v[k] = V;
                float4 o;
                o.x = clampf(S.x + V.x, 0.f, 63.f);
                o.y = clampf(S.y + V.y, 0.001f, 50.f);
                o.z = clampf(S.z + V.z, -0.99f, 0.99f);
                o.w = clampf(S.w + V.w, -0.99f, 0.99f);
                ns[k] = o;
            }
        }
        __syncthreads();   // all level-s reads done
        if (act) {
#pragma unroll
            for (int k = 0; k < 4; ++k) {
                st[k] = ns[k];
                buf[(4*rg + k)*TS + col] = ns[k];
            }
        }
        __syncthreads();   // level-(s+1) visible
    }

    // ---- store interior (cols [10,42), rows [10,26)) ----
    if (act && cin) {
#pragma unroll
        for (int k = 0; k < 4; ++k) {
            int r = 4*rg + k;
            if (r >= RLO && r < RHI) {
                int g = gidx[k];
                if (mu_out) {
                    mu_out[g] = st[k].x;     // final launch: only mu needed
                } else {
                    stO[g] = st[k];
                    vO[g]  = v[k];
                }
            }
        }
    }
}

// ---- global max(edge_weight); gmax pre-zeroed via hipMemsetAsync ----
// (0u is the order-preserving encoding of the most-negative float)
__global__ void reduce_max_kernel(const float* __restrict__ ew, unsigned int* gmax) {
    int i = blockIdx.x*blockDim.x + threadIdx.x;
    float m = -INFINITY;
    for (; i < NEDGE; i += gridDim.x*blockDim.x) m = fmaxf(m, ew[i]);
#pragma unroll
    for (int off = 32; off > 0; off >>= 1)
        m = fmaxf(m, __shfl_down(m, off, 64));
    if ((threadIdx.x & 63) == 0) {
        unsigned u = __float_as_uint(m);
        unsigned key = (u & 0x80000000u) ? ~u : (u | 0x80000000u);
        atomicMax(gmax, key);
    }
}

// init state + invariant coefficient plane
__global__ __launch_bounds__(256) void init_state_kernel(
    const float*  __restrict__ y,
    const float2* __restrict__ ew,
    const float2* __restrict__ uw,
    const unsigned int* __restrict__ gmax_enc,
    float4* stA, float4* c1)
{
    int idx = blockIdx.x*256 + threadIdx.x;

    unsigned key = *gmax_enc;
    unsigned u = (key & 0x80000000u) ? (key ^ 0x80000000u) : ~key;
    float gmax = __uint_as_float(u);
    float inv_denom = 1.f / (gmax*1.01f + 1.f);   // one-time, IEEE div fine

    float2 e   = ew[idx];
    float2 uwv = uw[idx];
    float  yv  = y[idx];
    float4 st;
    st.x = yv;
    st.y = 1.f;
    st.z = e.x * inv_denom;
    st.w = e.y * inv_denom;
    stA[idx] = st;
    c1[idx]  = make_float4(2.f*uwv.x, uwv.y*yv, e.x, e.y);
}

extern "C" void kernel_launch(void* const* d_in, const int* in_sizes, int n_in,
                              void* d_out, int out_size, void* d_ws, size_t ws_size,
                              hipStream_t stream) {
    const float* y  = (const float*)d_in[0];
    const float* ew = (const float*)d_in[1];
    const float* uw = (const float*)d_in[2];
    float* out = (float*)d_out;
    const int N = NPIX;

    // workspace: stA, stB, vA, vB, c1 (float4 planes) + 1 uint (~21 MB)
    float4* stA = (float4*)d_ws;
    float4* stB = stA + N;
    float4* vA  = stB + N;
    float4* vB  = vA + N;
    float4* c1  = vB + N;
    unsigned int* gmax = (unsigned int*)(c1 + N);

    hipMemsetAsync(gmax, 0, sizeof(unsigned int), stream);
    hipLaunchKernelGGL(reduce_max_kernel, dim3(512), dim3(256), 0, stream, ew, gmax);
    hipLaunchKernelGGL(init_state_kernel, dim3(N/256), dim3(256), 0, stream,
                       y, (const float2*)ew, (const float2*)uw, gmax,
                       stA, c1);

    float4 *stI = stA, *stO = stB, *vI = vA, *vO = vB;
    const int NLAUNCH = ITERS / T;   // 10
    for (int l = 0; l < NLAUNCH; ++l) {
        float* mo = (l == NLAUNCH-1) ? out : nullptr;
        // grid: 8 col-tiles x 16 row-tiles x 4 batch = 512 blocks
        hipLaunchKernelGGL(tile_kernel, dim3(8, 16, 4), dim3(512), 0, stream,
                           stI, vI, stO, vO, c1, mo, (l == 0) ? 1 : 0);
        float4* t;
        t = stI; stI = stO; stO = t;
        t = vI;  vI  = vO;  vO  = t;
    }
}